// Round 3
// baseline (79.555 us; speedup 1.0000x reference)
//
#include <hip/hip_runtime.h>

// Problem geometry (fixed by the reference):
//   x : (2, 8, 512, 512) f32, gm : (2, 1, 512, 512) f32
//   out = concat( bg:(2,8,512,512,16), on:(2,1,512,512,16) ) f32
// Key insight: hg==i, wg==j exactly -> splat is 1-D along r only; every
// output voxel is written by exactly one pixel. Pure streaming-write kernel.
//
// R3: grid-stride x4 (fewer waves, longer store streams), gm loads hoisted
// (latency amortized), nontemporal output stores via native clang vector
// type (HIP float4 is a class type the builtin rejects).

#define HW       (512 * 512)           // 262144 = 2^18
#define NPIX     (2 * HW)              // 524288 pixels total
#define QUADS    (NPIX * 4)            // 2,097,152 (pixel, r-chunk) pairs
#define BG_SIZE  (2 * 8 * HW * 16)     // 67,108,864 floats
#define ITER     4
#define STRIDE_P (NPIX / ITER)         // 131072 pixels between iterations

typedef float f32x4 __attribute__((ext_vector_type(4)));

__global__ __launch_bounds__(256) void splat_r_kernel(
    const float* __restrict__ x,
    const float* __restrict__ gm,
    float* __restrict__ out)
{
    // 4 threads per pixel; thread owns r-chunk q (4 floats, 16B).
    int g0    = blockIdx.x * 256 + threadIdx.x;  // quad id, iteration 0
    int q     = g0 & 3;
    int p0    = g0 >> 2;
    int rbase = q * 4;

    // Hoist all gm loads: independent, issue back-to-back at wave start.
    float pr[ITER];
    #pragma unroll
    for (int k = 0; k < ITER; ++k)
        pr[k] = gm[p0 + k * STRIDE_P] * 15.0f;

    #pragma unroll
    for (int k = 0; k < ITER; ++k) {
        int pixel = p0 + k * STRIDE_P;
        int n     = pixel >> 18;         // HW = 2^18
        int rem   = pixel & (HW - 1);    // i*512 + j

        float r0f = floorf(pr[k]);
        float t   = pr[k] - r0f;
        int   r0  = (int)r0f;
        int   i0  = min(max(r0,     0), 15);
        int   i1  = min(max(r0 + 1, 0), 15);
        float w0  = 1.0f - t;

        // statically-built weight vector for this thread's 4 r-slots
        f32x4 w;
        w.x = ((rbase + 0) == i0 ? w0 : 0.0f) + ((rbase + 0) == i1 ? t : 0.0f);
        w.y = ((rbase + 1) == i0 ? w0 : 0.0f) + ((rbase + 1) == i1 ? t : 0.0f);
        w.z = ((rbase + 2) == i0 ? w0 : 0.0f) + ((rbase + 2) == i1 ? t : 0.0f);
        w.w = ((rbase + 3) == i0 ? w0 : 0.0f) + ((rbase + 3) == i1 ? t : 0.0f);

        // bg channels: out[(((n*8+c)*HW + rem)*16) + rbase .. +3]
        const float* xp    = x + (n * 8) * HW + rem;
        int          obase = ((n * 8) * HW + rem) * 16 + rbase;
        #pragma unroll
        for (int c = 0; c < 8; ++c) {
            float v  = xp[c * HW];
            f32x4 o  = v * w;
            __builtin_nontemporal_store(o, (f32x4*)(out + obase + c * (HW * 16)));
        }

        // ones channel -> on[(pixel*16) + rbase .. +3] after bg block
        __builtin_nontemporal_store(w, (f32x4*)(out + BG_SIZE + pixel * 16 + rbase));
    }
}

extern "C" void kernel_launch(void* const* d_in, const int* in_sizes, int n_in,
                              void* d_out, int out_size, void* d_ws, size_t ws_size,
                              hipStream_t stream) {
    const float* x  = (const float*)d_in[0];
    const float* gm = (const float*)d_in[1];
    float* out = (float*)d_out;

    const int total_threads = QUADS / ITER;        // 524,288
    const int block = 256;
    const int grid  = total_threads / block;       // 2048
    splat_r_kernel<<<grid, block, 0, stream>>>(x, gm, out);
}

// Round 4
// 76.642 us; speedup vs baseline: 1.0380x; 1.0380x over previous
//
#include <hip/hip_runtime.h>

// Problem geometry (fixed by the reference):
//   x : (2, 8, 512, 512) f32, gm : (2, 1, 512, 512) f32
//   out = concat( bg:(2,8,512,512,16), on:(2,1,512,512,16) ) f32
// Key insight: hg==i, wg==j exactly -> splat is 1-D along r only; every
// output voxel is written by exactly one pixel. Pure streaming-write kernel.
//
// R4: plane-major decomposition. out = 18 planes (2n x 9ch) of 4 MB each.
// Each block writes a contiguous 32 KiB run of ONE plane; each wave emits a
// single contiguous 8 KiB store stream (fill-kernel-like), instead of R1's
// 9 interleaved streams 16 MB apart. gm/x re-reads are L2/L3-resident.

#define HW       (512 * 512)            // 262144 = 2^18
#define BG_SIZE  (2 * 8 * HW * 16)      // 67,108,864 floats
#define QPP      (HW * 4)               // quads (float4) per plane = 1,048,576
#define ITER     8
#define QPB      (256 * ITER)           // quads per block = 2048
#define BPP      (QPP / QPB)            // blocks per plane = 512
#define NPLANES  18

typedef float f32x4 __attribute__((ext_vector_type(4)));

__global__ __launch_bounds__(256) void splat_plane_kernel(
    const float* __restrict__ x,
    const float* __restrict__ gm,
    float* __restrict__ out)
{
    int blk   = blockIdx.x;
    int plane = blk >> 9;               // / BPP (512)
    int pbase = (blk & (BPP - 1)) * QPB;

    int n  = plane / 9;
    int ch = plane - n * 9;

    const float* gmn = gm + n * HW;
    const float* xp  = x + (n * 8 + ch) * HW;   // unused when ch==8
    float*       op  = (ch < 8) ? (out + (size_t)((n * 8 + ch) * HW) * 16)
                                : (out + BG_SIZE + (size_t)(n * HW) * 16);
    bool has_x = (ch < 8);

    #pragma unroll
    for (int k = 0; k < ITER; ++k) {
        int pq    = pbase + k * 256 + threadIdx.x;  // in-plane quad index
        int rem   = pq >> 2;                        // pixel within plane
        int rbase = (pq & 3) * 4;                   // r-chunk base

        float pr  = gmn[rem] * 15.0f;
        float r0f = floorf(pr);
        float t   = pr - r0f;
        int   r0  = (int)r0f;
        int   i0  = min(max(r0,     0), 15);
        int   i1  = min(max(r0 + 1, 0), 15);
        float w0  = 1.0f - t;

        f32x4 w;
        w.x = ((rbase + 0) == i0 ? w0 : 0.0f) + ((rbase + 0) == i1 ? t : 0.0f);
        w.y = ((rbase + 1) == i0 ? w0 : 0.0f) + ((rbase + 1) == i1 ? t : 0.0f);
        w.z = ((rbase + 2) == i0 ? w0 : 0.0f) + ((rbase + 2) == i1 ? t : 0.0f);
        w.w = ((rbase + 3) == i0 ? w0 : 0.0f) + ((rbase + 3) == i1 ? t : 0.0f);

        f32x4 o = w;
        if (has_x) {                    // wave-uniform branch (plane-constant)
            float v = xp[rem];
            o = v * w;
        }
        *(f32x4*)(op + (size_t)pq * 4) = o;
    }
}

extern "C" void kernel_launch(void* const* d_in, const int* in_sizes, int n_in,
                              void* d_out, int out_size, void* d_ws, size_t ws_size,
                              hipStream_t stream) {
    const float* x  = (const float*)d_in[0];
    const float* gm = (const float*)d_in[1];
    float* out = (float*)d_out;

    const int grid = NPLANES * BPP;     // 9216 blocks, 32 KiB each
    splat_plane_kernel<<<grid, 256, 0, stream>>>(x, gm, out);
}

// Round 5
// 69.311 us; speedup vs baseline: 1.1478x; 1.1058x over previous
//
#include <hip/hip_runtime.h>

// Problem geometry (fixed by the reference):
//   x : (2, 8, 512, 512) f32, gm : (2, 1, 512, 512) f32
//   out = concat( bg:(2,8,512,512,16), on:(2,1,512,512,16) ) f32
// Key insight: hg==i, wg==j exactly -> splat is 1-D along r only; every
// output voxel is written by exactly one pixel. Pure streaming-write kernel.
//
// R5: R1 structure, but each thread handles the SAME pixel offset in both
// batch elements (p in n=0, p+HW in n=1). All 18 loads (2 gm + 16 x,
// independent) issue before any store -> no vmcnt false deps (stores share
// the vmcnt counter with loads; R3/R4 interleaved loads after stores and
// paid for it). Store burst per wave doubles: CU->L2 write-port duty > 1.

#define HW      (512 * 512)           // 262144 = 2^18
#define BG_SIZE (2 * 8 * HW * 16)     // 67,108,864 floats

typedef float f32x4 __attribute__((ext_vector_type(4)));

__device__ __forceinline__ f32x4 make_weights(float pr, int rbase) {
    float r0f = floorf(pr);
    float t   = pr - r0f;
    int   r0  = (int)r0f;
    int   i0  = min(max(r0,     0), 15);
    int   i1  = min(max(r0 + 1, 0), 15);
    float w0  = 1.0f - t;
    f32x4 w;
    w.x = ((rbase + 0) == i0 ? w0 : 0.0f) + ((rbase + 0) == i1 ? t : 0.0f);
    w.y = ((rbase + 1) == i0 ? w0 : 0.0f) + ((rbase + 1) == i1 ? t : 0.0f);
    w.z = ((rbase + 2) == i0 ? w0 : 0.0f) + ((rbase + 2) == i1 ? t : 0.0f);
    w.w = ((rbase + 3) == i0 ? w0 : 0.0f) + ((rbase + 3) == i1 ? t : 0.0f);
    return w;
}

__global__ __launch_bounds__(256) void splat_r2_kernel(
    const float* __restrict__ x,
    const float* __restrict__ gm,
    float* __restrict__ out)
{
    int t     = blockIdx.x * 256 + threadIdx.x;   // 0 .. 1,048,575
    int q     = t & 3;
    int rbase = q * 4;
    int p     = t >> 2;                           // pixel 0 .. 262,143 (n=0)

    // ---- all loads first (independent; single vmcnt wait group) ----
    float ga = gm[p]      * 15.0f;                // n=0
    float gb = gm[HW + p] * 15.0f;                // n=1
    float xa[8], xb[8];
    #pragma unroll
    for (int c = 0; c < 8; ++c) {
        xa[c] = x[c * HW + p];                    // n=0 channels
        xb[c] = x[(8 + c) * HW + p];              // n=1 channels
    }

    f32x4 wa = make_weights(ga, rbase);
    f32x4 wb = make_weights(gb, rbase);

    // ---- all stores after (each wave-store = 1 KiB contiguous) ----
    #pragma unroll
    for (int c = 0; c < 8; ++c) {
        *(f32x4*)(out + ((size_t)(c * HW + p) * 16 + rbase))       = xa[c] * wa;
        *(f32x4*)(out + ((size_t)((8 + c) * HW + p) * 16 + rbase)) = xb[c] * wb;
    }
    *(f32x4*)(out + BG_SIZE + (size_t)p * 16 + rbase)        = wa;
    *(f32x4*)(out + BG_SIZE + (size_t)(HW + p) * 16 + rbase) = wb;
}

extern "C" void kernel_launch(void* const* d_in, const int* in_sizes, int n_in,
                              void* d_out, int out_size, void* d_ws, size_t ws_size,
                              hipStream_t stream) {
    const float* x  = (const float*)d_in[0];
    const float* gm = (const float*)d_in[1];
    float* out = (float*)d_out;

    const int total_threads = HW * 4;             // 1,048,576 (4 per pixel, n=0 half)
    const int block = 256;
    const int grid  = total_threads / block;      // 4096
    splat_r2_kernel<<<grid, block, 0, stream>>>(x, gm, out);
}